// Round 6
// baseline (37.840 us; speedup 1.0000x reference)
//
#include <hip/hip_runtime.h>

// HybridSampler: fused MLP (2->8 tanh -> 3 used outputs) + algebraically
// collapsed 2-qubit circuit + softmax(2). Element-PAIR vectorized so the
// backend emits packed fp32 (v_pk_fma_f32 / v_pk_mul_f32 / v_pk_add_f32)
// for all full-rate math; transcendentals (v_exp/v_sin/v_cos/v_rcp) stay scalar.
//
// Exact identities (see prior rounds):
//  - ry(w2, q0) cannot change qubit 1's marginal -> dropped.
//  - Marginal collapses to full-angle form:
//      AmB = ca*cb*cx1 - sb*(ca*sx1*cx0 - sa*sx0)
//      C2  = sb*cx0*cx1 + cb*sx1
//      Q   = C2*sd - AmB*cd     (= 1 - 2*P0);  out0 = 1/(1+exp(Q))
//  - tanh fold: angle_rev = b' + sum_j W2'_j * g_j,  g = 1/(1+2^t),
//      t = 2*log2e*u folded into W1/b1; INV_2PI folded into W2'/b'.
//  - Angles bounded -> |rev| < 0.9: raw v_sin/v_cos, no range reduction.

#define INV_2PI 0.15915494309189535f
#define TWO_LOG2E 2.8853900817779268f
#define LOG2E 1.4426950408889634f

typedef float v4f __attribute__((ext_vector_type(4)));
typedef float v2f __attribute__((ext_vector_type(2)));

struct Weights {
    float w1a[8], w1b[8], b1[8];   // 2*log2e * (W1 row0, W1 row1, b1)
    float w2a[8], w2b[8], w2d[8];  // -2*INV_2PI * W2 cols 0,1,3
    float b2a, b2b, b2d;           // INV_2PI * (b2 + colsum(W2)) for cols 0,1,3
};

__device__ __forceinline__ float rcp_fast(float x) {
    return __builtin_amdgcn_rcpf(x);   // v_rcp_f32
}
__device__ __forceinline__ float exp2_fast(float x) {
#if __has_builtin(__builtin_amdgcn_exp2f)
    return __builtin_amdgcn_exp2f(x);  // v_exp_f32
#else
    return __expf(x * 0.6931471805599453f);
#endif
}
__device__ __forceinline__ v2f sp(float s) { v2f v = {s, s}; return v; }
__device__ __forceinline__ v2f fma2(v2f a, v2f b, v2f c) {
    return __builtin_elementwise_fma(a, b, c);   // -> v_pk_fma_f32
}

// Process a PAIR of elements: x0/x1 hold the two elements' inputs lane-wise.
__device__ __forceinline__ void compute_pair(v2f x0, v2f x1, const Weights& W,
                                             v2f& o0, v2f& o1) {
    // ---- MLP in g-space ----
    v2f wa = sp(W.b2a), wb = sp(W.b2b), wd = sp(W.b2d);
#pragma unroll
    for (int j = 0; j < 8; ++j) {
        v2f t = fma2(x0, sp(W.w1a[j]), fma2(x1, sp(W.w1b[j]), sp(W.b1[j])));
        v2f e;  e.x = exp2_fast(t.x);  e.y = exp2_fast(t.y);
        v2f e1 = e + sp(1.0f);                       // v_pk_add_f32
        v2f g;  g.x = rcp_fast(e1.x);  g.y = rcp_fast(e1.y);
        wa = fma2(g, sp(W.w2a[j]), wa);
        wb = fma2(g, sp(W.w2b[j]), wb);
        wd = fma2(g, sp(W.w2d[j]), wd);
    }

    // ---- collapsed circuit (wa/wb/wd already in revolutions) ----
    v2f r0 = x0 * sp(INV_2PI), r1 = x1 * sp(INV_2PI);
    v2f sx0, cx0, sx1, cx1, sa, ca, sb, cb, sd, cd;
    sx0.x = __builtin_amdgcn_sinf(r0.x);  sx0.y = __builtin_amdgcn_sinf(r0.y);
    cx0.x = __builtin_amdgcn_cosf(r0.x);  cx0.y = __builtin_amdgcn_cosf(r0.y);
    sx1.x = __builtin_amdgcn_sinf(r1.x);  sx1.y = __builtin_amdgcn_sinf(r1.y);
    cx1.x = __builtin_amdgcn_cosf(r1.x);  cx1.y = __builtin_amdgcn_cosf(r1.y);
    sa.x  = __builtin_amdgcn_sinf(wa.x);  sa.y  = __builtin_amdgcn_sinf(wa.y);
    ca.x  = __builtin_amdgcn_cosf(wa.x);  ca.y  = __builtin_amdgcn_cosf(wa.y);
    sb.x  = __builtin_amdgcn_sinf(wb.x);  sb.y  = __builtin_amdgcn_sinf(wb.y);
    cb.x  = __builtin_amdgcn_cosf(wb.x);  cb.y  = __builtin_amdgcn_cosf(wb.y);
    sd.x  = __builtin_amdgcn_sinf(wd.x);  sd.y  = __builtin_amdgcn_sinf(wd.y);
    cd.x  = __builtin_amdgcn_cosf(wd.x);  cd.y  = __builtin_amdgcn_cosf(wd.y);

    v2f inner = fma2(ca * sx1, cx0, -(sa * sx0));
    v2f AmB   = fma2(-sb, inner, (ca * cb) * cx1);
    v2f C2    = fma2(sb * cx0, cx1, cb * sx1);
    v2f Q     = fma2(C2, sd, -(AmB * cd));        // in [-1,1]

    v2f qe = Q * sp(LOG2E);
    v2f ex; ex.x = exp2_fast(qe.x); ex.y = exp2_fast(qe.y);
    v2f ex1 = ex + sp(1.0f);
    o0.x = rcp_fast(ex1.x);  o0.y = rcp_fast(ex1.y);
    o1 = sp(1.0f) - o0;
}

__global__ __launch_bounds__(256) void HybridSampler_65481071406452_kernel(
    const float* __restrict__ in,   // [B,2]
    const float* __restrict__ W1,   // [2,8]
    const float* __restrict__ b1,   // [8]
    const float* __restrict__ W2,   // [8,4] row-major
    const float* __restrict__ b2,   // [4]
    float* __restrict__ out)        // [B,2]
{
    Weights W;
    float ta = 0.f, tb = 0.f, td = 0.f;
#pragma unroll
    for (int j = 0; j < 8; ++j) {
        W.w1a[j] = TWO_LOG2E * W1[j];
        W.w1b[j] = TWO_LOG2E * W1[8 + j];
        W.b1[j]  = TWO_LOG2E * b1[j];
        float a = W2[4 * j + 0], b = W2[4 * j + 1], d = W2[4 * j + 3];
        W.w2a[j] = -2.0f * INV_2PI * a;  ta += a;
        W.w2b[j] = -2.0f * INV_2PI * b;  tb += b;
        W.w2d[j] = -2.0f * INV_2PI * d;  td += d;
    }
    W.b2a = INV_2PI * (b2[0] + ta);
    W.b2b = INV_2PI * (b2[1] + tb);
    W.b2d = INV_2PI * (b2[3] + td);

    int tid = blockIdx.x * 256 + threadIdx.x;   // B % 4 == 0: no tail
    const v4f* in4 = reinterpret_cast<const v4f*>(in);
    v4f* out4 = reinterpret_cast<v4f*>(out);

    v4f va = __builtin_nontemporal_load(&in4[tid * 2]);
    v4f vb = __builtin_nontemporal_load(&in4[tid * 2 + 1]);

    // pair0 = elements {0,1}; pair1 = elements {2,3}
    v2f p0x0 = {va.x, va.z}, p0x1 = {va.y, va.w};
    v2f p1x0 = {vb.x, vb.z}, p1x1 = {vb.y, vb.w};

    v2f a0, a1, b0, b1v;
    compute_pair(p0x0, p0x1, W, a0, a1);
    compute_pair(p1x0, p1x1, W, b0, b1v);

    v4f oa = {a0.x, a1.x, a0.y, a1.y};
    v4f ob = {b0.x, b1v.x, b0.y, b1v.y};
    __builtin_nontemporal_store(oa, &out4[tid * 2]);
    __builtin_nontemporal_store(ob, &out4[tid * 2 + 1]);
}

extern "C" void kernel_launch(void* const* d_in, const int* in_sizes, int n_in,
                              void* d_out, int out_size, void* d_ws, size_t ws_size,
                              hipStream_t stream) {
    const float* in = (const float*)d_in[0];
    const float* W1 = (const float*)d_in[1];
    const float* b1 = (const float*)d_in[2];
    const float* W2 = (const float*)d_in[3];
    const float* b2 = (const float*)d_in[4];
    float* out = (float*)d_out;

    int B = in_sizes[0] / 2;                 // 2,097,152 (divisible by 4)
    int threads = B / 4;                     // 4 elements per thread
    int blocks = threads / 256;              // 2048 blocks of 256
    HybridSampler_65481071406452_kernel<<<blocks, 256, 0, stream>>>(in, W1, b1, W2, b2, out);
}

// Round 7
// 15.138 us; speedup vs baseline: 2.4997x; 2.4997x over previous
//
#include <hip/hip_runtime.h>

// HybridSampler: fused MLP (2->8 tanh -> 3 used outputs) + algebraically
// collapsed 2-qubit circuit + softmax(2).
//
// Exact identities:
//  - ry(w2, q0) acts only on qubit 0 -> cannot change qubit 1's marginal -> dropped.
//  - Circuit marginal (full-angle form):
//      AmB = ca*cb*cx1 - sb*(ca*sx1*cx0 - sa*sx0)
//      C2  = sb*cx0*cx1 + cb*sx1
//      Q   = C2*sd - AmB*cd            (= 1 - 2*P0)
//      out0 = 1/(1+exp(Q)), out1 = 1-out0
//  - tanh fold: h = tanh(u) = 1 - 2*g with g = 1/(1+2^(2*log2e*u)).
//      angle = b + sum_j W2_j*h_j  ==>  angle_rev = b' + sum_j W2'_j*g_j
//      with  b'  = INV_2PI*(b + sum_j W2_j),  W2'_j = -2*INV_2PI*W2_j,
//      so v_exp needs no log2e mul and v_sin/v_cos take revolutions directly.
//  - Angles bounded (|x|<~5.5, |w|<~2.5) -> |rev|<0.9: no range reduction needed.
//
// R6 note: element-pair v2f packing for v_pk_fma_f32 REGRESSED 15.1->37.8 us
// (scalarization + insert/extract overhead). Keep the scalar form.

#define INV_2PI 0.15915494309189535f
#define TWO_LOG2E 2.8853900817779268f
#define LOG2E 1.4426950408889634f

typedef float v4f __attribute__((ext_vector_type(4)));

struct Weights {
    float w1a[8], w1b[8], b1[8];   // 2*log2e * (W1 row0, W1 row1, b1)
    float w2a[8], w2b[8], w2d[8];  // -2*INV_2PI * W2 cols 0,1,3
    float b2a, b2b, b2d;           // INV_2PI * (b2 + colsum(W2)) for cols 0,1,3
};

__device__ __forceinline__ float rcp_fast(float x) {
    return __builtin_amdgcn_rcpf(x);   // v_rcp_f32
}

__device__ __forceinline__ float exp2_fast(float x) {
#if __has_builtin(__builtin_amdgcn_exp2f)
    return __builtin_amdgcn_exp2f(x);  // v_exp_f32 (natively 2^x)
#else
    return __expf(x * 0.6931471805599453f);
#endif
}

__device__ __forceinline__ float2 compute_one(float x0, float x1, const Weights& W) {
    // ---- MLP in g-space: angle_rev = b' + sum W2'_j * g_j ----
    float wa = W.b2a, wb = W.b2b, wd = W.b2d;
#pragma unroll
    for (int j = 0; j < 8; ++j) {
        float t = fmaf(x0, W.w1a[j], fmaf(x1, W.w1b[j], W.b1[j]));  // 2*log2e*u
        float g = rcp_fast(1.0f + exp2_fast(t));
        wa = fmaf(g, W.w2a[j], wa);
        wb = fmaf(g, W.w2b[j], wb);
        wd = fmaf(g, W.w2d[j], wd);
    }

    // ---- collapsed circuit; wa/wb/wd already in revolutions ----
    float r0 = x0 * INV_2PI, r1 = x1 * INV_2PI;
    float sx0 = __builtin_amdgcn_sinf(r0), cx0 = __builtin_amdgcn_cosf(r0);
    float sx1 = __builtin_amdgcn_sinf(r1), cx1 = __builtin_amdgcn_cosf(r1);
    float sa  = __builtin_amdgcn_sinf(wa), ca  = __builtin_amdgcn_cosf(wa);
    float sb  = __builtin_amdgcn_sinf(wb), cb  = __builtin_amdgcn_cosf(wb);
    float sd  = __builtin_amdgcn_sinf(wd), cd  = __builtin_amdgcn_cosf(wd);

    float inner = fmaf(ca * sx1, cx0, -(sa * sx0));
    float AmB   = fmaf(-sb, inner, (ca * cb) * cx1);
    float C2    = fmaf(sb * cx0, cx1, cb * sx1);
    float Q     = fmaf(C2, sd, -(AmB * cd));   // in [-1,1]

    float o0 = rcp_fast(1.0f + exp2_fast(Q * LOG2E));
    return make_float2(o0, 1.0f - o0);
}

__global__ __launch_bounds__(256) void HybridSampler_65481071406452_kernel(
    const float* __restrict__ in,   // [B,2]
    const float* __restrict__ W1,   // [2,8]
    const float* __restrict__ b1,   // [8]
    const float* __restrict__ W2,   // [8,4] row-major
    const float* __restrict__ b2,   // [4]
    float* __restrict__ out)        // [B,2]
{
    Weights W;
    float sa = 0.f, sb = 0.f, sd = 0.f;
#pragma unroll
    for (int j = 0; j < 8; ++j) {
        W.w1a[j] = TWO_LOG2E * W1[j];
        W.w1b[j] = TWO_LOG2E * W1[8 + j];
        W.b1[j]  = TWO_LOG2E * b1[j];
        float a = W2[4 * j + 0], b = W2[4 * j + 1], d = W2[4 * j + 3];
        W.w2a[j] = -2.0f * INV_2PI * a;  sa += a;
        W.w2b[j] = -2.0f * INV_2PI * b;  sb += b;
        W.w2d[j] = -2.0f * INV_2PI * d;  sd += d;
    }
    W.b2a = INV_2PI * (b2[0] + sa);
    W.b2b = INV_2PI * (b2[1] + sb);
    W.b2d = INV_2PI * (b2[3] + sd);

    int tid = blockIdx.x * 256 + threadIdx.x;   // B % 4 == 0: no tail
    const v4f* in4 = reinterpret_cast<const v4f*>(in);
    v4f* out4 = reinterpret_cast<v4f*>(out);

    v4f va = __builtin_nontemporal_load(&in4[tid * 2]);
    v4f vb = __builtin_nontemporal_load(&in4[tid * 2 + 1]);

    float2 r0 = compute_one(va.x, va.y, W);
    float2 r1 = compute_one(va.z, va.w, W);
    float2 r2 = compute_one(vb.x, vb.y, W);
    float2 r3 = compute_one(vb.z, vb.w, W);

    v4f oa = {r0.x, r0.y, r1.x, r1.y};
    v4f ob = {r2.x, r2.y, r3.x, r3.y};
    __builtin_nontemporal_store(oa, &out4[tid * 2]);
    __builtin_nontemporal_store(ob, &out4[tid * 2 + 1]);
}

extern "C" void kernel_launch(void* const* d_in, const int* in_sizes, int n_in,
                              void* d_out, int out_size, void* d_ws, size_t ws_size,
                              hipStream_t stream) {
    const float* in = (const float*)d_in[0];
    const float* W1 = (const float*)d_in[1];
    const float* b1 = (const float*)d_in[2];
    const float* W2 = (const float*)d_in[3];
    const float* b2 = (const float*)d_in[4];
    float* out = (float*)d_out;

    int B = in_sizes[0] / 2;                 // 2,097,152 (divisible by 4)
    int threads = B / 4;                     // 4 elements per thread
    int blocks = threads / 256;              // 2048 blocks of 256
    HybridSampler_65481071406452_kernel<<<blocks, 256, 0, stream>>>(in, W1, b1, W2, b2, out);
}